// Round 4
// baseline (345.569 us; speedup 1.0000x reference)
//
#include <hip/hip_runtime.h>
#include <hip/hip_bf16.h>
#include <math.h>

#define HEADS 8
#define CH    512
#define S     1024
#define NKV   320
#define DH    64
#define BATCH 32

typedef __attribute__((ext_vector_type(8))) short short8;
typedef __attribute__((ext_vector_type(4))) short short4v;
typedef __attribute__((ext_vector_type(4))) float float4v;

__device__ __forceinline__ short f2bf(float f) {
    __hip_bfloat16 h = __float2bfloat16(f);
    return *reinterpret_cast<short*>(&h);
}
__device__ __forceinline__ float bf2f(short s) {
    union { int i; float f; } u;
    u.i = ((int)(unsigned short)s) << 16;
    return u.f;
}

// async global->LDS DMA, 16B/lane. LDS base must be wave-uniform; HW adds lane*16.
#define GLOAD_LDS16(gp, lp) __builtin_amdgcn_global_load_lds( \
    (const __attribute__((address_space(1))) void*)(gp),      \
    (__attribute__((address_space(3))) void*)(lp), 16, 0, 0)

// ---------------------------------------------------------------------------
// Flat fp32 -> bf16 cast. n divisible by 1024.
// ---------------------------------------------------------------------------
__global__ __launch_bounds__(256) void castw(const float* __restrict__ in,
                                             short* __restrict__ out, int n) {
    const int i = (blockIdx.x * 256 + threadIdx.x) * 4;
    if (i < n) {
        const float4 v = *(const float4*)&in[i];
        short4v p = {f2bf(v.x), f2bf(v.y), f2bf(v.z), f2bf(v.w)};
        *(short4v*)&out[i] = p;
    }
}

// ---------------------------------------------------------------------------
// prep: read x [b][512 c][1024 hw] ONCE; emit
//   xT  [b][1024 s][512 c] bf16   (transpose-cast)
//   xpT [b][320 n][512 c]  bf16   (pooled: mean-w | mean-h | 2x2avg, transposed)
// Block = (cg of 64 c, b); 4 chunks of 256 hw (=8 h-rows) staged in LDS bf16.
// Pools computed from bf16 tile (error ~0.4% rel, inside threshold budget).
// ---------------------------------------------------------------------------
__global__ __launch_bounds__(256) void prep(const float* __restrict__ x,
                                            short* __restrict__ xT,
                                            short* __restrict__ xpT) {
    __shared__ short sm[64 * 260];           // 260 = 256 + 4 pad (8B-aligned rows)
    const int t = threadIdx.x, lane = t & 63, w = t >> 6;
    const int b = blockIdx.y, cg = blockIdx.x;
    const float* xb = x + ((size_t)(b * 512 + cg * 64)) * 1024;
    short* xTb = xT + ((size_t)b * 1024) * 512 + cg * 64;
    short* xpb = xpT + ((size_t)b * 320) * 512 + cg * 64;
    float twacc[8];
    #pragma unroll
    for (int j = 0; j < 8; ++j) twacc[j] = 0.f;

    for (int ci = 0; ci < 4; ++ci) {
        const int hw0 = ci * 256;
        // load & convert: wave w handles c-rows {i*4+w}, lanes cover 256 hw
        #pragma unroll
        for (int i = 0; i < 16; ++i) {
            const int c = i * 4 + w;
            const float4 v = *(const float4*)&xb[(size_t)c * 1024 + hw0 + lane * 4];
            short4v p = {f2bf(v.x), f2bf(v.y), f2bf(v.z), f2bf(v.w)};
            *(short4v*)&sm[c * 260 + lane * 4] = p;
        }
        __syncthreads();
        // xT: thread t owns s = hw0 + t; gather LDS column t (2-way, free)
        {
            short rowv[64];
            #pragma unroll
            for (int c = 0; c < 64; ++c) rowv[c] = sm[c * 260 + t];
            short* dst = &xTb[(size_t)(hw0 + t) * 512];
            #pragma unroll
            for (int v8 = 0; v8 < 8; ++v8)
                *(short8*)&dst[v8 * 8] = *(short8*)&rowv[v8 * 8];
        }
        // pools: c = lane, group = w
        #pragma unroll
        for (int hh = 0; hh < 2; ++hh) {           // th (mean over w), h complete
            const int h = w * 2 + hh;
            float s = 0.f;
            #pragma unroll
            for (int ww = 0; ww < 32; ++ww) s += bf2f(sm[lane * 260 + h * 32 + ww]);
            xpb[(size_t)(ci * 8 + h) * 512 + lane] = f2bf(s * (1.0f / 32.0f));
        }
        #pragma unroll
        for (int j = 0; j < 8; ++j) {              // tw (mean over h), accumulate
            const int ww = w * 8 + j;
            float s = 0.f;
            #pragma unroll
            for (int h = 0; h < 8; ++h) s += bf2f(sm[lane * 260 + h * 32 + ww]);
            twacc[j] += s;
        }
        #pragma unroll
        for (int pw = 0; pw < 16; ++pw) {          // tp (2x2 avg), ph complete
            const int base = lane * 260 + (w * 2) * 32 + pw * 2;
            const float s = bf2f(sm[base]) + bf2f(sm[base + 1]) +
                            bf2f(sm[base + 32]) + bf2f(sm[base + 33]);
            xpb[(size_t)(64 + (ci * 4 + w) * 16 + pw) * 512 + lane] = f2bf(s * 0.25f);
        }
        __syncthreads();
    }
    #pragma unroll
    for (int j = 0; j < 8; ++j) {
        const int ww = w * 8 + j;
        xpb[(size_t)(32 + ww) * 512 + lane] = f2bf(twacc[j] * (1.0f / 32.0f));
    }
}

// ---------------------------------------------------------------------------
// bf16 MFMA GEMM: Out[bz][row][col] = act( sum_k A[bz][row][k]*B[bz][col][k] )
// A [*,M,K], B [*,N,K] both K-contiguous bf16, K=512. 256 thr = 4 waves (2x2),
// XOR-swizzled global_load_lds staging (b128 frag reads 2-way-free).
// ACT: 0 none(bf16), 1 sigmoid+0.125 on col<512(bf16), 2 +bias[row](fp32).
// ---------------------------------------------------------------------------
template <int MT, int NT, int ACT, typename OT>
__global__ __launch_bounds__(256) void gemm_bf16(const short* __restrict__ A, long sAb,
                                                 const short* __restrict__ B, long sBb,
                                                 const float* __restrict__ bias,
                                                 OT* __restrict__ C, int M, int N) {
    constexpr int K  = 512;
    constexpr int BM = 32 * MT, BN = 32 * NT;
    __shared__ short As[BM * 64];
    __shared__ short Bs[BN * 64];
    const int t = threadIdx.x, w = t >> 6, l = t & 63;
    const int wm = w >> 1, wn = w & 1, quad = l >> 4, m15 = l & 15;
    const int bz = blockIdx.z;
    const int n0 = blockIdx.x * BN, m0 = blockIdx.y * BM;
    const short* gA = A + (size_t)sAb * bz + (size_t)m0 * K;
    const short* gB = B + (size_t)sBb * bz + (size_t)n0 * K;
    const int lrow = l >> 3;
    const int pc   = l & 7;

    const float4v zf = {0.f, 0.f, 0.f, 0.f};
    float4v acc[MT][NT];
    #pragma unroll
    for (int i = 0; i < MT; ++i)
        #pragma unroll
        for (int j = 0; j < NT; ++j) acc[i][j] = zf;

    for (int k0 = 0; k0 < K; k0 += 64) {
        #pragma unroll
        for (int ii = w; ii < BM / 8; ii += 4) {
            const int row = ii * 8 + lrow;
            const int xx = pc ^ (row & 7);
            GLOAD_LDS16(gA + (size_t)row * K + k0 + xx * 8, &As[ii * 512]);
        }
        #pragma unroll
        for (int ii = w; ii < BN / 8; ii += 4) {
            const int row = ii * 8 + lrow;
            const int xx = pc ^ (row & 7);
            GLOAD_LDS16(gB + (size_t)row * K + k0 + xx * 8, &Bs[ii * 512]);
        }
        __syncthreads();
        #pragma unroll
        for (int ks = 0; ks < 2; ++ks) {
            const int xa = (((ks * 4 + quad) ^ (m15 & 7))) * 8;
            short8 aF[MT], bF[NT];
            #pragma unroll
            for (int i = 0; i < MT; ++i)
                aF[i] = *(const short8*)&As[((wm * MT + i) * 16 + m15) * 64 + xa];
            #pragma unroll
            for (int j = 0; j < NT; ++j)
                bF[j] = *(const short8*)&Bs[((wn * NT + j) * 16 + m15) * 64 + xa];
            #pragma unroll
            for (int i = 0; i < MT; ++i)
                #pragma unroll
                for (int j = 0; j < NT; ++j)
                    acc[i][j] = __builtin_amdgcn_mfma_f32_16x16x32_bf16(aF[i], bF[j], acc[i][j], 0, 0, 0);
        }
        __syncthreads();
    }

    OT* gC = C + (size_t)bz * M * N;
    #pragma unroll
    for (int i = 0; i < MT; ++i) {
        #pragma unroll
        for (int r = 0; r < 4; ++r) {
            const int row = m0 + (wm * MT + i) * 16 + quad * 4 + r;
            float bv = 0.f;
            if (ACT == 2) bv = bias[row];
            #pragma unroll
            for (int j = 0; j < NT; ++j) {
                const int col = n0 + (wn * NT + j) * 16 + m15;
                float v = acc[i][j][r];
                if (ACT == 1) { v = 1.0f / (1.0f + __expf(-v)); if (col < 512) v *= 0.125f; }
                if (ACT == 2) v += bv;
                if constexpr (sizeof(OT) == 2)
                    ((short*)gC)[(size_t)row * N + col] = f2bf(v);
                else
                    ((float*)gC)[(size_t)row * N + col] = v;
            }
        }
    }
}

// ---------------------------------------------------------------------------
// MFMA attention. 8 waves per (b, h, 128-s tile). qT [b][s][c] bf16 (A-frags
// direct from global), kvT [b][n][ckv] bf16 (k pre-scaled 0.125), pos bf16.
// V global reads PREFETCHED before QK^T (hide HBM latency); LDS write deferred
// past the K-read barrier. P roundtrips wave-private LDS. Out aoT bf16.
// ---------------------------------------------------------------------------
__global__ __launch_bounds__(512, 4) void attn_mfma(const short* __restrict__ qT,
                                                    const short* __restrict__ kvT,
                                                    const short* __restrict__ posb,
                                                    short* __restrict__ aoT) {
    __shared__ short smP[8 * 16 * 72];    // 18432 B
    __shared__ short smB[64 * 344];       // 44032 B: K [8][320][8] then V^T [64][344]
    const int tid = threadIdx.x, w = tid >> 6, l = tid & 63;
    const int quad = l >> 4, m15 = l & 15;
    const int b = blockIdx.z, h = blockIdx.y, s0 = blockIdx.x * 128;
    const short* kvb = kvT + (size_t)b * NKV * 1024;

    // ---- stage K via global_load_lds: smB[dg][320 n][8] ----
    for (int i2 = w; i2 < 40; i2 += 8) {
        const int nb = i2 % 5, dg = i2 / 5;
        GLOAD_LDS16(kvb + (size_t)(nb * 64 + l) * 1024 + h * 64 + dg * 8,
                    &smB[(dg * 320 + nb * 64) * 8]);
    }
    // ---- prefetch V (independent of K region; written to LDS after barrier)
    short8 vpf[5];
    int vn[5], vd8[5];
    #pragma unroll
    for (int it = 0; it < 5; ++it) {
        const int i2 = it * 512 + tid;
        const int n5 = i2 & 31, d8 = (i2 >> 5) & 7, nb = i2 >> 8;
        const int n = nb * 32 + n5;
        vn[it] = n; vd8[it] = d8;
        vpf[it] = *(const short8*)&kvb[(size_t)n * 1024 + 512 + h * 64 + d8 * 8];
    }
    // ---- Q A-frags straight from global ----
    const short* qb = qT + (size_t)(b * S + s0 + w * 16 + m15) * 512 + h * 64;
    const short8 aQ0 = *(const short8*)&qb[quad * 8];
    const short8 aQ1 = *(const short8*)&qb[32 + quad * 8];
    __syncthreads();

    const float4v zf = {0.f, 0.f, 0.f, 0.f};
    float4v acc[20];
    #pragma unroll
    for (int tt = 0; tt < 20; ++tt) acc[tt] = zf;

    #pragma unroll
    for (int tt = 0; tt < 20; ++tt) {
        const short8 b0 = *(const short8*)&smB[(quad * 320 + tt * 16 + m15) * 8];
        const short8 b1 = *(const short8*)&smB[((4 + quad) * 320 + tt * 16 + m15) * 8];
        acc[tt] = __builtin_amdgcn_mfma_f32_16x16x32_bf16(aQ0, b0, acc[tt], 0, 0, 0);
        acc[tt] = __builtin_amdgcn_mfma_f32_16x16x32_bf16(aQ1, b1, acc[tt], 0, 0, 0);
    }

    // ---- + pos (bf16), row max, exp, row sum ----
    const int srow = s0 + w * 16 + quad * 4;
    float mrow[4] = {-1e30f, -1e30f, -1e30f, -1e30f};
    #pragma unroll
    for (int tt = 0; tt < 20; ++tt) {
        #pragma unroll
        for (int r = 0; r < 4; ++r) {
            const float sc = acc[tt][r] + bf2f(posb[(size_t)(srow + r) * NKV + tt * 16 + m15]);
            acc[tt][r] = sc;
            mrow[r] = fmaxf(mrow[r], sc);
        }
    }
    #pragma unroll
    for (int r = 0; r < 4; ++r) {
        #pragma unroll
        for (int off = 1; off < 16; off <<= 1)
            mrow[r] = fmaxf(mrow[r], __shfl_xor(mrow[r], off, 16));
    }
    float lrow[4] = {0.f, 0.f, 0.f, 0.f};
    #pragma unroll
    for (int tt = 0; tt < 20; ++tt) {
        #pragma unroll
        for (int r = 0; r < 4; ++r) {
            const float p = __expf(acc[tt][r] - mrow[r]);
            acc[tt][r] = p;
            lrow[r] += p;
        }
    }
    #pragma unroll
    for (int r = 0; r < 4; ++r) {
        #pragma unroll
        for (int off = 1; off < 16; off <<= 1)
            lrow[r] += __shfl_xor(lrow[r], off, 16);
    }

    __syncthreads();   // all waves done reading K from smB

    // ---- write prefetched V^T [64][344] ----
    #pragma unroll
    for (int it = 0; it < 5; ++it) {
        #pragma unroll
        for (int e = 0; e < 8; ++e)
            smB[(vd8[it] * 8 + e) * 344 + vn[it]] = vpf[it][e];
    }
    __syncthreads();

    // ---- P@V via wave-private LDS roundtrip ----
    short* Pw = &smP[w * 16 * 72];
    float4v O[4];
    #pragma unroll
    for (int dt = 0; dt < 4; ++dt) O[dt] = zf;
    #pragma unroll
    for (int c = 0; c < 5; ++c) {
        #pragma unroll
        for (int tt = 0; tt < 4; ++tt) {
            #pragma unroll
            for (int r = 0; r < 4; ++r)
                Pw[(quad * 4 + r) * 72 + tt * 16 + m15] = f2bf(acc[4 * c + tt][r]);
        }
        #pragma unroll
        for (int ks = 0; ks < 2; ++ks) {
            const short8 aP = *(const short8*)&Pw[m15 * 72 + ks * 32 + quad * 8];
            #pragma unroll
            for (int dt = 0; dt < 4; ++dt) {
                const short8 bV = *(const short8*)&smB[(dt * 16 + m15) * 344 + c * 64 + ks * 32 + quad * 8];
                O[dt] = __builtin_amdgcn_mfma_f32_16x16x32_bf16(aP, bV, O[dt], 0, 0, 0);
            }
        }
    }

    // ---- normalize + direct bf16 output aoT[b][s][c] ----
    float inv[4];
    #pragma unroll
    for (int r = 0; r < 4; ++r) inv[r] = 1.0f / lrow[r];
    #pragma unroll
    for (int dt = 0; dt < 4; ++dt) {
        #pragma unroll
        for (int r = 0; r < 4; ++r) {
            const int s = s0 + w * 16 + quad * 4 + r;
            aoT[(size_t)(b * S + s) * 512 + h * 64 + dt * 16 + m15] = f2bf(O[dt][r] * inv[r]);
        }
    }
}

// ---------------------------------------------------------------------------
extern "C" void kernel_launch(void* const* d_in, const int* in_sizes, int n_in,
                              void* d_out, int out_size, void* d_ws, size_t ws_size,
                              hipStream_t stream) {
    const float* x    = (const float*)d_in[0];
    const float* Wqkv = (const float*)d_in[1];
    const float* Wout = (const float*)d_in[2];
    const float* bout = (const float*)d_in[3];
    const float* pos  = (const float*)d_in[4];
    char* ws = (char*)d_ws;
    short* xT   = (short*)(ws + 0);            // [32][1024][512] bf16 33554432 B
    short* xpT  = (short*)(ws + 33554432);     // [32][320][512] bf16  10485760 B
    short* qT   = (short*)(ws + 44040192);     // [32][1024][512] bf16 33554432 B
    short* kvT  = (short*)(ws + 77594624);     // [32][320][1024] bf16 20971520 B
    short* aoT  = (short*)(ws + 98566144);     // [32][1024][512] bf16 33554432 B
    short* Wbf  = (short*)(ws + 132120576);    // [1536][512] bf16      1572864 B
    short* Wobf = (short*)(ws + 133693440);    // [512][512] bf16        524288 B
    short* posb = (short*)(ws + 134217728);    // [1024][320] bf16       655360 B
    float* out  = (float*)d_out;

    castw<<<dim3(768), 256, 0, stream>>>(Wqkv, Wbf, 1536 * 512);
    castw<<<dim3(256), 256, 0, stream>>>(Wout, Wobf, 512 * 512);
    castw<<<dim3(320), 256, 0, stream>>>(pos, posb, S * NKV);
    prep<<<dim3(8, BATCH), 256, 0, stream>>>(x, xT, xpT);
    // qT[b][s][c] = xT . Wq
    gemm_bf16<4, 4, 0, short><<<dim3(4, 8, BATCH), 256, 0, stream>>>(
        xT, (long)S * CH, Wbf, 0, nullptr, qT, S, CH);
    // kvT[b][n][ckv] = sigmoid(xpT . Wkv), k-cols pre-scaled 0.125
    gemm_bf16<2, 8, 1, short><<<dim3(4, 5, BATCH), 256, 0, stream>>>(
        xpT, (long)NKV * CH, Wbf + CH * CH, 0, nullptr, kvT, NKV, 2 * CH);
    attn_mfma<<<dim3(8, HEADS, BATCH), 512, 0, stream>>>(qT, kvT, posb, aoT);
    // out[b][c][s] = Wout . aoT + bout  (fp32, direct coalesced)
    gemm_bf16<4, 4, 2, float><<<dim3(8, 4, BATCH), 256, 0, stream>>>(
        Wobf, 0, aoT, (long)S * CH, bout, out, CH, S);
}

// Round 5
// 324.696 us; speedup vs baseline: 1.0643x; 1.0643x over previous
//
#include <hip/hip_runtime.h>
#include <hip/hip_bf16.h>
#include <math.h>

#define HEADS 8
#define CH    512
#define S     1024
#define NKV   320
#define DH    64
#define BATCH 32

typedef __attribute__((ext_vector_type(8))) short short8;
typedef __attribute__((ext_vector_type(4))) short short4v;
typedef __attribute__((ext_vector_type(4))) float float4v;

__device__ __forceinline__ short f2bf(float f) {
    __hip_bfloat16 h = __float2bfloat16(f);
    return *reinterpret_cast<short*>(&h);
}
__device__ __forceinline__ float bf2f(short s) {
    union { int i; float f; } u;
    u.i = ((int)(unsigned short)s) << 16;
    return u.f;
}

// async global->LDS DMA, 16B/lane. LDS base must be wave-uniform; HW adds lane*16.
#define GLOAD_LDS16(gp, lp) __builtin_amdgcn_global_load_lds( \
    (const __attribute__((address_space(1))) void*)(gp),      \
    (__attribute__((address_space(3))) void*)(lp), 16, 0, 0)

// ---------------------------------------------------------------------------
// One fused fp32->bf16 cast for Wqkv (786432) + Wout (262144) + pos (327680).
// Boundaries are block-aligned (768 / 1024 / 1344 blocks) -> uniform branches.
// ---------------------------------------------------------------------------
__global__ __launch_bounds__(256) void castall(const float* __restrict__ Wqkv,
                                               const float* __restrict__ Wout,
                                               const float* __restrict__ pos,
                                               short* __restrict__ Wbf,
                                               short* __restrict__ Wobf,
                                               short* __restrict__ posb) {
    const int i = (blockIdx.x * 256 + threadIdx.x) * 4;
    const float* src;
    short* dst;
    int off;
    if (i < 786432)       { src = Wqkv; dst = Wbf;  off = 0; }
    else if (i < 1048576) { src = Wout; dst = Wobf; off = 786432; }
    else                  { src = pos;  dst = posb; off = 1048576; }
    const float4 v = *(const float4*)&src[i - off];
    short4v p = {f2bf(v.x), f2bf(v.y), f2bf(v.z), f2bf(v.w)};
    *(short4v*)&dst[i - off] = p;
}

// ---------------------------------------------------------------------------
// prep: read x [b][512 c][1024 hw] ONCE; emit
//   xT  [b][1024 s][512 c] bf16   (transpose-cast)
//   xpT [b][320 n][512 c]  bf16   (pooled: mean-w | mean-h | 2x2avg, transposed)
// ---------------------------------------------------------------------------
__global__ __launch_bounds__(256) void prep(const float* __restrict__ x,
                                            short* __restrict__ xT,
                                            short* __restrict__ xpT) {
    __shared__ short sm[64 * 260];
    const int t = threadIdx.x, lane = t & 63, w = t >> 6;
    const int b = blockIdx.y, cg = blockIdx.x;
    const float* xb = x + ((size_t)(b * 512 + cg * 64)) * 1024;
    short* xTb = xT + ((size_t)b * 1024) * 512 + cg * 64;
    short* xpb = xpT + ((size_t)b * 320) * 512 + cg * 64;
    float twacc[8];
    #pragma unroll
    for (int j = 0; j < 8; ++j) twacc[j] = 0.f;

    for (int ci = 0; ci < 4; ++ci) {
        const int hw0 = ci * 256;
        #pragma unroll
        for (int i = 0; i < 16; ++i) {
            const int c = i * 4 + w;
            const float4 v = *(const float4*)&xb[(size_t)c * 1024 + hw0 + lane * 4];
            short4v p = {f2bf(v.x), f2bf(v.y), f2bf(v.z), f2bf(v.w)};
            *(short4v*)&sm[c * 260 + lane * 4] = p;
        }
        __syncthreads();
        {
            short rowv[64];
            #pragma unroll
            for (int c = 0; c < 64; ++c) rowv[c] = sm[c * 260 + t];
            short* dst = &xTb[(size_t)(hw0 + t) * 512];
            #pragma unroll
            for (int v8 = 0; v8 < 8; ++v8)
                *(short8*)&dst[v8 * 8] = *(short8*)&rowv[v8 * 8];
        }
        #pragma unroll
        for (int hh = 0; hh < 2; ++hh) {
            const int h = w * 2 + hh;
            float s = 0.f;
            #pragma unroll
            for (int ww = 0; ww < 32; ++ww) s += bf2f(sm[lane * 260 + h * 32 + ww]);
            xpb[(size_t)(ci * 8 + h) * 512 + lane] = f2bf(s * (1.0f / 32.0f));
        }
        #pragma unroll
        for (int j = 0; j < 8; ++j) {
            const int ww = w * 8 + j;
            float s = 0.f;
            #pragma unroll
            for (int h = 0; h < 8; ++h) s += bf2f(sm[lane * 260 + h * 32 + ww]);
            twacc[j] += s;
        }
        #pragma unroll
        for (int pw = 0; pw < 16; ++pw) {
            const int base = lane * 260 + (w * 2) * 32 + pw * 2;
            const float s = bf2f(sm[base]) + bf2f(sm[base + 1]) +
                            bf2f(sm[base + 32]) + bf2f(sm[base + 33]);
            xpb[(size_t)(64 + (ci * 4 + w) * 16 + pw) * 512 + lane] = f2bf(s * 0.25f);
        }
        __syncthreads();
    }
    #pragma unroll
    for (int j = 0; j < 8; ++j) {
        const int ww = w * 8 + j;
        xpb[(size_t)(32 + ww) * 512 + lane] = f2bf(twacc[j] * (1.0f / 32.0f));
    }
}

// ---------------------------------------------------------------------------
// bf16 MFMA GEMM, DOUBLE-BUFFERED global_load_lds staging:
//   stage(k+1) into buf^1 -> compute buf -> one barrier per 64-K iter.
// The barrier's vmcnt(0) drain overlaps the whole MFMA tile compute (the
// fix for the 2-barrier m97-structure stall at small shapes).
// Out[bz][row][col] = act( sum_k A[bz][row][k]*B[bz][col][k] ), K=512.
// ACT: 0 none(bf16), 1 sigmoid+0.125 on col<512(bf16), 2 +bias[row](fp32).
// ---------------------------------------------------------------------------
template <int MT, int NT, int ACT, typename OT>
__global__ __launch_bounds__(256) void gemm_bf16(const short* __restrict__ A, long sAb,
                                                 const short* __restrict__ B, long sBb,
                                                 const float* __restrict__ bias,
                                                 OT* __restrict__ C, int M, int N) {
    constexpr int K  = 512;
    constexpr int BM = 32 * MT, BN = 32 * NT;
    __shared__ short As[2][BM * 64];
    __shared__ short Bs[2][BN * 64];
    const int t = threadIdx.x, w = t >> 6, l = t & 63;
    const int wm = w >> 1, wn = w & 1, quad = l >> 4, m15 = l & 15;
    const int bz = blockIdx.z;
    const int n0 = blockIdx.x * BN, m0 = blockIdx.y * BM;
    const short* gA = A + (size_t)sAb * bz + (size_t)m0 * K;
    const short* gB = B + (size_t)sBb * bz + (size_t)n0 * K;
    const int lrow = l >> 3;
    const int pc   = l & 7;

    const float4v zf = {0.f, 0.f, 0.f, 0.f};
    float4v acc[MT][NT];
    #pragma unroll
    for (int i = 0; i < MT; ++i)
        #pragma unroll
        for (int j = 0; j < NT; ++j) acc[i][j] = zf;

    auto stage = [&](int buf, int k0) {
        #pragma unroll
        for (int ii = w; ii < BM / 8; ii += 4) {
            const int row = ii * 8 + lrow;
            const int xx = pc ^ (row & 7);
            GLOAD_LDS16(gA + (size_t)row * K + k0 + xx * 8, &As[buf][ii * 512]);
        }
        #pragma unroll
        for (int ii = w; ii < BN / 8; ii += 4) {
            const int row = ii * 8 + lrow;
            const int xx = pc ^ (row & 7);
            GLOAD_LDS16(gB + (size_t)row * K + k0 + xx * 8, &Bs[buf][ii * 512]);
        }
    };

    stage(0, 0);
    __syncthreads();                       // drains the first DMA group
    for (int k0 = 0; k0 < K; k0 += 64) {
        const int cur = (k0 >> 6) & 1;
        if (k0 + 64 < K) stage(cur ^ 1, k0 + 64);   // in flight during compute
        #pragma unroll
        for (int ks = 0; ks < 2; ++ks) {
            const int xa = (((ks * 4 + quad) ^ (m15 & 7))) * 8;
            short8 aF[MT], bF[NT];
            #pragma unroll
            for (int i = 0; i < MT; ++i)
                aF[i] = *(const short8*)&As[cur][((wm * MT + i) * 16 + m15) * 64 + xa];
            #pragma unroll
            for (int j = 0; j < NT; ++j)
                bF[j] = *(const short8*)&Bs[cur][((wn * NT + j) * 16 + m15) * 64 + xa];
            #pragma unroll
            for (int i = 0; i < MT; ++i)
                #pragma unroll
                for (int j = 0; j < NT; ++j)
                    acc[i][j] = __builtin_amdgcn_mfma_f32_16x16x32_bf16(aF[i], bF[j], acc[i][j], 0, 0, 0);
        }
        __syncthreads();                   // guards buf reuse + drains next DMA
    }

    OT* gC = C + (size_t)bz * M * N;
    #pragma unroll
    for (int i = 0; i < MT; ++i) {
        #pragma unroll
        for (int r = 0; r < 4; ++r) {
            const int row = m0 + (wm * MT + i) * 16 + quad * 4 + r;
            float bv = 0.f;
            if (ACT == 2) bv = bias[row];
            #pragma unroll
            for (int j = 0; j < NT; ++j) {
                const int col = n0 + (wn * NT + j) * 16 + m15;
                float v = acc[i][j][r];
                if (ACT == 1) { v = 1.0f / (1.0f + __expf(-v)); if (col < 512) v *= 0.125f; }
                if (ACT == 2) v += bv;
                if constexpr (sizeof(OT) == 2)
                    ((short*)gC)[(size_t)row * N + col] = f2bf(v);
                else
                    ((float*)gC)[(size_t)row * N + col] = v;
            }
        }
    }
}

// ---------------------------------------------------------------------------
// MFMA attention. 8 waves per (b, h, 128-s tile). qT [b][s][c] bf16 (A-frags
// direct from global), kvT [b][n][ckv] bf16 (k pre-scaled 0.125), pos bf16.
// V loads issued AFTER the first barrier -> in flight across QK^T+softmax,
// drained for free at the second barrier. No softmax max-pass (scores bounded
// |sc| <~ 25; exp fp32-safe; identical after l-normalization).
// ---------------------------------------------------------------------------
__global__ __launch_bounds__(512) void attn_mfma(const short* __restrict__ qT,
                                                 const short* __restrict__ kvT,
                                                 const short* __restrict__ posb,
                                                 short* __restrict__ aoT) {
    __shared__ short smP[8 * 16 * 72];    // 18432 B
    __shared__ short smB[64 * 344];       // 44032 B: K [8][320][8] then V^T [64][344]
    const int tid = threadIdx.x, w = tid >> 6, l = tid & 63;
    const int quad = l >> 4, m15 = l & 15;
    const int b = blockIdx.z, h = blockIdx.y, s0 = blockIdx.x * 128;
    const short* kvb = kvT + (size_t)b * NKV * 1024;

    // ---- stage K via global_load_lds: smB[dg][320 n][8] ----
    for (int i2 = w; i2 < 40; i2 += 8) {
        const int nb = i2 % 5, dg = i2 / 5;
        GLOAD_LDS16(kvb + (size_t)(nb * 64 + l) * 1024 + h * 64 + dg * 8,
                    &smB[(dg * 320 + nb * 64) * 8]);
    }
    // ---- Q A-frags straight from global ----
    const short* qb = qT + (size_t)(b * S + s0 + w * 16 + m15) * 512 + h * 64;
    const short8 aQ0 = *(const short8*)&qb[quad * 8];
    const short8 aQ1 = *(const short8*)&qb[32 + quad * 8];
    __syncthreads();

    // ---- V prefetch issued HERE: overlaps QK^T+softmax, drained at barrier 2
    short8 vpf[5];
    #pragma unroll
    for (int it = 0; it < 5; ++it) {
        const int i2 = it * 512 + tid;
        const int n = (i2 >> 8) * 32 + (i2 & 31), d8 = (i2 >> 5) & 7;
        vpf[it] = *(const short8*)&kvb[(size_t)n * 1024 + 512 + h * 64 + d8 * 8];
    }

    const float4v zf = {0.f, 0.f, 0.f, 0.f};
    float4v acc[20];
    #pragma unroll
    for (int tt = 0; tt < 20; ++tt) acc[tt] = zf;

    #pragma unroll
    for (int tt = 0; tt < 20; ++tt) {
        const short8 b0 = *(const short8*)&smB[(quad * 320 + tt * 16 + m15) * 8];
        const short8 b1 = *(const short8*)&smB[((4 + quad) * 320 + tt * 16 + m15) * 8];
        acc[tt] = __builtin_amdgcn_mfma_f32_16x16x32_bf16(aQ0, b0, acc[tt], 0, 0, 0);
        acc[tt] = __builtin_amdgcn_mfma_f32_16x16x32_bf16(aQ1, b1, acc[tt], 0, 0, 0);
    }

    // ---- + pos (bf16), exp, row sum (no max-subtraction needed) ----
    const int srow = s0 + w * 16 + quad * 4;
    float lrow[4] = {0.f, 0.f, 0.f, 0.f};
    #pragma unroll
    for (int tt = 0; tt < 20; ++tt) {
        #pragma unroll
        for (int r = 0; r < 4; ++r) {
            const float p = __expf(acc[tt][r] +
                                   bf2f(posb[(size_t)(srow + r) * NKV + tt * 16 + m15]));
            acc[tt][r] = p;
            lrow[r] += p;
        }
    }
    #pragma unroll
    for (int r = 0; r < 4; ++r) {
        #pragma unroll
        for (int off = 1; off < 16; off <<= 1)
            lrow[r] += __shfl_xor(lrow[r], off, 16);
    }

    __syncthreads();   // all waves done reading K; V loads drained here

    // ---- write prefetched V^T [64][344] ----
    #pragma unroll
    for (int it = 0; it < 5; ++it) {
        const int i2 = it * 512 + tid;
        const int n = (i2 >> 8) * 32 + (i2 & 31), d8 = (i2 >> 5) & 7;
        #pragma unroll
        for (int e = 0; e < 8; ++e)
            smB[(d8 * 8 + e) * 344 + n] = vpf[it][e];
    }
    __syncthreads();

    // ---- P@V via wave-private LDS roundtrip ----
    short* Pw = &smP[w * 16 * 72];
    float4v O[4];
    #pragma unroll
    for (int dt = 0; dt < 4; ++dt) O[dt] = zf;
    #pragma unroll
    for (int c = 0; c < 5; ++c) {
        #pragma unroll
        for (int tt = 0; tt < 4; ++tt) {
            #pragma unroll
            for (int r = 0; r < 4; ++r)
                Pw[(quad * 4 + r) * 72 + tt * 16 + m15] = f2bf(acc[4 * c + tt][r]);
        }
        #pragma unroll
        for (int ks = 0; ks < 2; ++ks) {
            const short8 aP = *(const short8*)&Pw[m15 * 72 + ks * 32 + quad * 8];
            #pragma unroll
            for (int dt = 0; dt < 4; ++dt) {
                const short8 bV = *(const short8*)&smB[(dt * 16 + m15) * 344 + c * 64 + ks * 32 + quad * 8];
                O[dt] = __builtin_amdgcn_mfma_f32_16x16x32_bf16(aP, bV, O[dt], 0, 0, 0);
            }
        }
    }

    // ---- normalize + direct bf16 output aoT[b][s][c] ----
    float inv[4];
    #pragma unroll
    for (int r = 0; r < 4; ++r) inv[r] = 1.0f / lrow[r];
    #pragma unroll
    for (int dt = 0; dt < 4; ++dt) {
        #pragma unroll
        for (int r = 0; r < 4; ++r) {
            const int s = s0 + w * 16 + quad * 4 + r;
            aoT[(size_t)(b * S + s) * 512 + h * 64 + dt * 16 + m15] = f2bf(O[dt][r] * inv[r]);
        }
    }
}

// ---------------------------------------------------------------------------
extern "C" void kernel_launch(void* const* d_in, const int* in_sizes, int n_in,
                              void* d_out, int out_size, void* d_ws, size_t ws_size,
                              hipStream_t stream) {
    const float* x    = (const float*)d_in[0];
    const float* Wqkv = (const float*)d_in[1];
    const float* Wout = (const float*)d_in[2];
    const float* bout = (const float*)d_in[3];
    const float* pos  = (const float*)d_in[4];
    char* ws = (char*)d_ws;
    short* xT   = (short*)(ws + 0);            // [32][1024][512] bf16 33554432 B
    short* xpT  = (short*)(ws + 33554432);     // [32][320][512] bf16  10485760 B
    short* qT   = (short*)(ws + 44040192);     // [32][1024][512] bf16 33554432 B
    short* kvT  = (short*)(ws + 77594624);     // [32][320][1024] bf16 20971520 B
    short* aoT  = (short*)(ws + 98566144);     // [32][1024][512] bf16 33554432 B
    short* Wbf  = (short*)(ws + 132120576);    // [1536][512] bf16      1572864 B
    short* Wobf = (short*)(ws + 133693440);    // [512][512] bf16        524288 B
    short* posb = (short*)(ws + 134217728);    // [1024][320] bf16       655360 B
    float* out  = (float*)d_out;

    castall<<<dim3(1344), 256, 0, stream>>>(Wqkv, Wout, pos, Wbf, Wobf, posb);
    prep<<<dim3(8, BATCH), 256, 0, stream>>>(x, xT, xpT);
    // qT[b][s][c] = xT . Wq
    gemm_bf16<4, 4, 0, short><<<dim3(4, 8, BATCH), 256, 0, stream>>>(
        xT, (long)S * CH, Wbf, 0, nullptr, qT, S, CH);
    // kvT[b][n][ckv] = sigmoid(xpT . Wkv), k-cols pre-scaled 0.125  (64x128 tile)
    gemm_bf16<2, 4, 1, short><<<dim3(8, 5, BATCH), 256, 0, stream>>>(
        xpT, (long)NKV * CH, Wbf + CH * CH, 0, nullptr, kvT, NKV, 2 * CH);
    attn_mfma<<<dim3(8, HEADS, BATCH), 512, 0, stream>>>(qT, kvT, posb, aoT);
    // out[b][c][s] = Wout . aoT + bout  (fp32, direct coalesced)
    gemm_bf16<4, 4, 2, float><<<dim3(8, 4, BATCH), 256, 0, stream>>>(
        Wobf, 0, aoT, (long)S * CH, bout, out, CH, S);
}